// Round 15
// baseline (200.133 us; speedup 1.0000x reference)
//
#include <hip/hip_runtime.h>

#define N_NODES 100000
#define N_EDGES 1250000
#define D_IN 64
#define D_HID 32
#define D_OUT 41
#define NBUK 784           // buckets of 128 nodes: 784*128 = 100352 >= 100000
#define BSH 7
#define PARTB 256          // partition blocks; each owns a private slice per bucket
#define BCHUNK 4883        // ceil(1.25M/256)
#define SCAP 32            // slice capacity: mean 6.23, tail ~0; 128B = 2 lines
#define BSTR 8192          // ints per bucket region = PARTB*SCAP (32KB/bucket)
#define PBLK 782           // proj blocks: 782*128 = 100096 rows (covers zero row)
#define ROWCAP 48          // per-node list capacity (Poisson(12.5) tail ~1e-15)
#define LSTR 88            // LDS row stride in shorts (MFMA tiles)
#define OSTR 72            // LDS out-tile row stride in shorts (144B, 16B-aligned)
#define ZERO_OFF 6400000   // byte offset of the all-zeros row (row 100000 * 64B)
#define SENT 0x01000000u   // valid edge words are < this; poison 0xAAAAAAAA is not

typedef short bf16x8 __attribute__((ext_vector_type(8)));
typedef float f32x4 __attribute__((ext_vector_type(4)));
typedef unsigned int u32x4 __attribute__((ext_vector_type(4)));  // clang-native

__device__ __forceinline__ float bflo(unsigned int u) {
    union { unsigned int i; float f; } v; v.i = u << 16; return v.f;
}
__device__ __forceinline__ float bfhi(unsigned int u) {
    union { unsigned int i; float f; } v; v.i = u & 0xffff0000u; return v.f;
}
__device__ __forceinline__ unsigned short f2bf(float f) {
    union { float f; unsigned int i; } v; v.f = f;
    unsigned int x = v.i;
    return (unsigned short)((x + 0x7fffu + ((x >> 16) & 1u)) >> 16);  // RNE
}
__device__ __forceinline__ void acc8(float* a, uint4 u) {
    a[0] += bflo(u.x); a[1] += bfhi(u.x);
    a[2] += bflo(u.y); a[3] += bfhi(u.y);
    a[4] += bflo(u.z); a[5] += bfhi(u.z);
    a[6] += bflo(u.w); a[7] += bfhi(u.w);
}
__device__ __forceinline__ int padded8(int d) {
    int dd = d < ROWCAP ? d : ROWCAP;
    int p = (dd + 7) & ~7;
    if (p == 0) p = 8;
    return p;
}
// nontemporal 16B store via clang-native vector type (uint4 is a class and
// is rejected by the builtin). Streaming data nobody re-reads in THIS
// kernel; keeps L2 free for the random gathers (table > per-XCD L2).
__device__ __forceinline__ void nt_store4(uint4 v, void* p) {
    u32x4 w; w.x = v.x; w.y = v.y; w.z = v.z; w.w = v.w;
    __builtin_nontemporal_store(w, (u32x4*)p);
}
__device__ __forceinline__ void nt_store1(unsigned int v, void* p) {
    __builtin_nontemporal_store(v, (unsigned int*)p);
}
__device__ __forceinline__ void nt_storef(float v, float* p) {
    __builtin_nontemporal_store(v, p);
}

// one 8-wide gather chunk (offsets from row[i..i+7]) from a 64B-row table.
__device__ __forceinline__ void chunk8(const int* row, int i, const char* tab,
                                       int qb, float* a) {
    int4 o0 = *(const int4*)(row + i);
    int4 o1 = *(const int4*)(row + i + 4);
    uint4 u0 = *(const uint4*)(tab + o0.x + qb);
    uint4 u1 = *(const uint4*)(tab + o0.y + qb);
    uint4 u2 = *(const uint4*)(tab + o0.z + qb);
    uint4 u3 = *(const uint4*)(tab + o0.w + qb);
    uint4 u4 = *(const uint4*)(tab + o1.x + qb);
    uint4 u5 = *(const uint4*)(tab + o1.y + qb);
    uint4 u6 = *(const uint4*)(tab + o1.z + qb);
    uint4 u7 = *(const uint4*)(tab + o1.w + qb);
    acc8(a, u0); acc8(a, u1); acc8(a, u2); acc8(a, u3);
    acc8(a, u4); acc8(a, u5); acc8(a, u6); acc8(a, u7);
}

// insert one slice word (if valid, i.e. below the poison sentinel) into lists.
__device__ __forceinline__ void ins(unsigned int w, int* lists, int* lcnt) {
    if (w < SENT) {
        int dl = (int)(w >> 17);
        int p = atomicAdd(&lcnt[dl], 1);
        if (p < ROWCAP) lists[dl * ROWCAP + p] = (int)((w & 0x1FFFFu) << 6);
    }
}

// ---- fused front (round-8 verified best + nt stores): blocks [0,PARTB)
// partition edges into private 2-line bucket slices (LDS counter only, zero
// global atomics, poison-sentinel slice lengths); blocks [PARTB,PARTB+782)
// do the 128-row MFMA projection [xl|xr] = x @ [W1l|W1r] (+b1 into xr). ----
__global__ __launch_bounds__(256) void k_front(const int* __restrict__ src,
                                               const int* __restrict__ dst,
                                               unsigned int* __restrict__ buckets,
                                               const float* __restrict__ x,
                                               const float* __restrict__ W1l,
                                               const float* __restrict__ W1r,
                                               const float* __restrict__ b1,
                                               unsigned short* __restrict__ xl,
                                               unsigned short* __restrict__ xr) {
    __shared__ short smem[128 * LSTR + 64 * LSTR];   // proj tiles; part aliases
    int tid = threadIdx.x;
    if (blockIdx.x < PARTB) {
        // ---------------- single-pass private-slice partition ----------------
        int* lcnt = (int*)smem;             // [NBUK] per-block slice counters
        int bid = blockIdx.x;
        for (int i = tid; i < NBUK; i += 256) lcnt[i] = 0;
        __syncthreads();
        int e0 = bid * BCHUNK;
        int e1 = e0 + BCHUNK; if (e1 > N_EDGES) e1 = N_EDGES;
        int e = e0 + tid;
        for (; e + 768 < e1; e += 1024) {
            int d0 = dst[e],       s0 = src[e];
            int d1 = dst[e + 256], s1 = src[e + 256];
            int d2 = dst[e + 512], s2 = src[e + 512];
            int d3 = dst[e + 768], s3 = src[e + 768];
            int b0 = d0 >> BSH, p0 = atomicAdd(&lcnt[b0], 1);
            if (p0 < SCAP) nt_store1(
                (unsigned int)s0 | ((unsigned int)(d0 & 127) << 17),
                &buckets[(size_t)b0 * BSTR + bid * SCAP + p0]);
            int b1i = d1 >> BSH, p1 = atomicAdd(&lcnt[b1i], 1);
            if (p1 < SCAP) nt_store1(
                (unsigned int)s1 | ((unsigned int)(d1 & 127) << 17),
                &buckets[(size_t)b1i * BSTR + bid * SCAP + p1]);
            int b2 = d2 >> BSH, p2 = atomicAdd(&lcnt[b2], 1);
            if (p2 < SCAP) nt_store1(
                (unsigned int)s2 | ((unsigned int)(d2 & 127) << 17),
                &buckets[(size_t)b2 * BSTR + bid * SCAP + p2]);
            int b3 = d3 >> BSH, p3 = atomicAdd(&lcnt[b3], 1);
            if (p3 < SCAP) nt_store1(
                (unsigned int)s3 | ((unsigned int)(d3 & 127) << 17),
                &buckets[(size_t)b3 * BSTR + bid * SCAP + p3]);
        }
        for (; e < e1; e += 256) {
            int d = dst[e], s = src[e];
            int b = d >> BSH;
            int p = atomicAdd(&lcnt[b], 1);
            if (p < SCAP) nt_store1(
                (unsigned int)s | ((unsigned int)(d & 127) << 17),
                &buckets[(size_t)b * BSTR + bid * SCAP + p]);
        }
        return;
    }
    // ---------------- MFMA projection (128 rows/block) ----------------
    short* sX  = smem;                    // 128 x LSTR
    short* sWT = smem + 128 * LSTR;       // 64 x LSTR
    int n0 = (blockIdx.x - PARTB) * 128;
    for (int i = tid; i < 1024; i += 256) {
        int k = i >> 4, c4 = i & 15;
        float4 v = (c4 < 8) ? ((const float4*)W1l)[k * 8 + c4]
                            : ((const float4*)W1r)[k * 8 + (c4 - 8)];
        int col = c4 * 4;
        sWT[(col + 0) * LSTR + k] = (short)f2bf(v.x);
        sWT[(col + 1) * LSTR + k] = (short)f2bf(v.y);
        sWT[(col + 2) * LSTR + k] = (short)f2bf(v.z);
        sWT[(col + 3) * LSTR + k] = (short)f2bf(v.w);
    }
    {
        int g = tid >> 1, q2 = tid & 1;   // 2 lanes/row, 32 floats each
        int n = n0 + g;
        short pk[32];
        if (n < N_NODES) {
            const float4* xp = (const float4*)(x + (size_t)n * D_IN + q2 * 32);
#pragma unroll
            for (int i = 0; i < 8; ++i) {
                float4 f = xp[i];
                pk[i * 4 + 0] = (short)f2bf(f.x);
                pk[i * 4 + 1] = (short)f2bf(f.y);
                pk[i * 4 + 2] = (short)f2bf(f.z);
                pk[i * 4 + 3] = (short)f2bf(f.w);
            }
        } else {
#pragma unroll
            for (int i = 0; i < 32; ++i) pk[i] = 0;
        }
        short* sp = sX + g * LSTR + q2 * 32;
        *(bf16x8*)(sp)      = *(bf16x8*)(pk);
        *(bf16x8*)(sp + 8)  = *(bf16x8*)(pk + 8);
        *(bf16x8*)(sp + 16) = *(bf16x8*)(pk + 16);
        *(bf16x8*)(sp + 24) = *(bf16x8*)(pk + 24);
    }
    __syncthreads();
    int wid = tid >> 6, lane = tid & 63;
    int quad = lane >> 4, lc = lane & 15;
    // load BOTH row-half A-fragments before aliasing sX with the out tile
    const short* saA = sX + (wid * 16 + lc) * LSTR + quad * 8;
    const short* saB = sX + ((wid + 4) * 16 + lc) * LSTR + quad * 8;
    bf16x8 afA0 = *(const bf16x8*)(saA);
    bf16x8 afA1 = *(const bf16x8*)(saA + 32);
    bf16x8 afB0 = *(const bf16x8*)(saB);
    bf16x8 afB1 = *(const bf16x8*)(saB + 32);
    __syncthreads();                        // all frags in regs; sX reusable
    short* sO = sX;                         // 128 x OSTR out tile (18.4KB <= sX)
#pragma unroll
    for (int mm = 0; mm < 2; ++mm) {
        int m0 = (wid + mm * 4) * 16;
        bf16x8 af0 = mm ? afB0 : afA0;
        bf16x8 af1 = mm ? afB1 : afA1;
#pragma unroll
        for (int t = 0; t < 4; ++t) {
            const short* sbp = sWT + (t * 16 + lc) * LSTR + quad * 8;
            bf16x8 bf0 = *(const bf16x8*)(sbp);
            bf16x8 bf1 = *(const bf16x8*)(sbp + 32);
            f32x4 acc = {0.f, 0.f, 0.f, 0.f};
            acc = __builtin_amdgcn_mfma_f32_16x16x32_bf16(af0, bf0, acc, 0, 0, 0);
            acc = __builtin_amdgcn_mfma_f32_16x16x32_bf16(af1, bf1, acc, 0, 0, 0);
            int col = t * 16 + lc;
            float bias = (col >= 32) ? b1[col - 32] : 0.f;
#pragma unroll
            for (int r = 0; r < 4; ++r)
                sO[(m0 + (quad << 2) + r) * OSTR + col] = (short)f2bf(acc[r] + bias);
        }
    }
    __syncthreads();
    {
        int g = tid >> 1, q2 = tid & 1;     // q2=0 -> xl row, q2=1 -> xr row
        int n = n0 + g;
        const short* srow = sO + g * OSTR + q2 * 32;
        uint4 v0, v1, v2, v3;
        if (n < N_NODES) {
            v0 = *(const uint4*)(srow);
            v1 = *(const uint4*)(srow + 8);
            v2 = *(const uint4*)(srow + 16);
            v3 = *(const uint4*)(srow + 24);
        } else {
            v0 = v1 = v2 = v3 = make_uint4(0, 0, 0, 0);  // zero rows incl. ZERO_OFF
        }
        char* base = (char*)(q2 ? xr : xl) + ((size_t)n << 6);
        nt_store4(v0, base);
        nt_store4(v1, base + 16);
        nt_store4(v2, base + 32);
        nt_store4(v3, base + 48);
    }
}

// ---- layer1 (round-8 structure + nt stores): one 256-thread block per
// 128-node bucket. Dense coalesced sentinel-scan -> LDS lists -> predicated
// nt dump over the bucket region (alias; reads done) -> dual-node chunk8
// gather -> h = bf16(relu(mean + xr)), h stored nontemporal so the xl
// gather table keeps the L2. ----
__global__ __launch_bounds__(256) void k_bagg1(unsigned int* __restrict__ bukspace,
                                               const unsigned short* __restrict__ xl,
                                               const unsigned short* __restrict__ xr,
                                               unsigned short* __restrict__ h,
                                               int* __restrict__ gcnt) {
    __shared__ int lists[128 * ROWCAP];
    __shared__ int lcnt[128];
    int tid = threadIdx.x, b = blockIdx.x;
    if (tid < 128) lcnt[tid] = 0;
    __syncthreads();
    const uint4* bk4 = (const uint4*)(bukspace + (size_t)b * BSTR);
#pragma unroll
    for (int k = 0; k < BSTR / 4 / 256; ++k) {      // 8 coalesced uint4/thread
        uint4 w = bk4[tid + k * 256];
        ins(w.x, lists, lcnt);
        ins(w.y, lists, lcnt);
        ins(w.z, lists, lcnt);
        ins(w.w, lists, lcnt);
    }
    __syncthreads();
    if (tid < 128) {
        int c = lcnt[tid];
        int cc = c < ROWCAP ? c : ROWCAP;
        int ce = (cc + 7) & ~7;
        if (ce == 0) ce = 8;                // min-pad: chunk 0 always valid
        for (int s = cc; s < ce; ++s) lists[tid * ROWCAP + s] = ZERO_OFF;
    }
    __syncthreads();
    int nbase = b << BSH;
    // predicated nt dump over the (fully consumed) bucket region: glists alias
    int* glists = (int*)(bukspace + (size_t)b * BSTR);
    for (int i4 = tid; i4 < 128 * 12; i4 += 256) {
        int li = i4 / 12, c4 = i4 % 12;
        if (c4 * 4 < padded8(lcnt[li]))
            nt_store4(*(const uint4*)(lists + li * ROWCAP + c4 * 4),
                      glists + li * ROWCAP + c4 * 4);
    }
    if (tid < 128) nt_store1((unsigned int)lcnt[tid],
                             (unsigned int*)&gcnt[nbase + tid]);
    // dual-node chunk8 gather
    int g = tid >> 2, q = tid & 3, qb = q << 4;
    int nA = nbase + g, nB = nbase + g + 64;
    int dA = lcnt[g], dB = lcnt[g + 64];
    int pA = padded8(dA), pB = padded8(dB);
    const int* rowA = lists + g * ROWCAP;
    const int* rowB = lists + (g + 64) * ROWCAP;
    const char* xlb = (const char*)xl;
    float a[8] = {0.f, 0.f, 0.f, 0.f, 0.f, 0.f, 0.f, 0.f};
    float c[8] = {0.f, 0.f, 0.f, 0.f, 0.f, 0.f, 0.f, 0.f};
    chunk8(rowA, 0, xlb, qb, a);
    chunk8(rowB, 0, xlb, qb, c);
    for (int i = 8; i < pA; i += 8) chunk8(rowA, i, xlb, qb, a);
    for (int i = 8; i < pB; i += 8) chunk8(rowB, i, xlb, qb, c);
#pragma unroll
    for (int half = 0; half < 2; ++half) {
        int n = half ? nB : nA;
        int d = half ? dB : dA;
        const float* ar = half ? c : a;
        if (n >= N_NODES) {
            nt_store4(make_uint4(0, 0, 0, 0), (char*)h + ((size_t)n << 6) + qb);
            continue;
        }
        float inv = 1.0f / fmaxf((float)d, 1.0f);
        uint4 rr = *(const uint4*)((const char*)xr + ((size_t)n << 6) + qb);
        float o0 = fmaxf(ar[0] * inv + bflo(rr.x), 0.f);
        float o1 = fmaxf(ar[1] * inv + bfhi(rr.x), 0.f);
        float o2 = fmaxf(ar[2] * inv + bflo(rr.y), 0.f);
        float o3 = fmaxf(ar[3] * inv + bfhi(rr.y), 0.f);
        float o4 = fmaxf(ar[4] * inv + bflo(rr.z), 0.f);
        float o5 = fmaxf(ar[5] * inv + bfhi(rr.z), 0.f);
        float o6 = fmaxf(ar[6] * inv + bflo(rr.w), 0.f);
        float o7 = fmaxf(ar[7] * inv + bfhi(rr.w), 0.f);
        uint4 o;
        o.x = ((unsigned int)f2bf(o1) << 16) | f2bf(o0);
        o.y = ((unsigned int)f2bf(o3) << 16) | f2bf(o2);
        o.z = ((unsigned int)f2bf(o5) << 16) | f2bf(o4);
        o.w = ((unsigned int)f2bf(o7) << 16) | f2bf(o6);
        nt_store4(o, (char*)h + ((size_t)n << 6) + qb);
    }
}

// ---- layer2 (round-8 structure + nt stores): lists read directly from the
// glists alias (19.7KB LDS, high occupancy), dual-node chunk8 gather over h,
// then 2x 64-row MFMA epilogue: out = [mean|h] @ [W2l;W2r] + b2; out stored
// nontemporal so the h gather table keeps the L2. ----
__global__ __launch_bounds__(256) void k_bagg2(const unsigned int* __restrict__ bukspace,
                                               const int* __restrict__ gcnt,
                                               const unsigned short* __restrict__ h,
                                               const float* __restrict__ W2l,
                                               const float* __restrict__ b2,
                                               const float* __restrict__ W2r,
                                               float* __restrict__ out) {
    __shared__ short sBT[48 * LSTR];
    __shared__ short sA[64 * LSTR];
    int tid = threadIdx.x, b = blockIdx.x;
    int nbase = b << BSH;
    for (int i = tid; i < 48 * 64; i += 256) {
        int col = i >> 6, kk = i & 63;
        float v = 0.f;
        if (col < D_OUT) v = (kk < 32) ? W2l[kk * D_OUT + col] : W2r[(kk - 32) * D_OUT + col];
        sBT[col * LSTR + kk] = (short)f2bf(v);
    }
    const int* glists = (const int*)(bukspace + (size_t)b * BSTR);
    int g = tid >> 2, q = tid & 3, qb = q << 4;
    int dA = gcnt[nbase + g], dB = gcnt[nbase + g + 64];
    int pA = padded8(dA), pB = padded8(dB);
    const int* rowA = glists + g * ROWCAP;
    const int* rowB = glists + (g + 64) * ROWCAP;
    const char* hb = (const char*)h;
    float a[8] = {0.f, 0.f, 0.f, 0.f, 0.f, 0.f, 0.f, 0.f};
    float c[8] = {0.f, 0.f, 0.f, 0.f, 0.f, 0.f, 0.f, 0.f};
    chunk8(rowA, 0, hb, qb, a);
    chunk8(rowB, 0, hb, qb, c);
    for (int i = 8; i < pA; i += 8) chunk8(rowA, i, hb, qb, a);
    for (int i = 8; i < pB; i += 8) chunk8(rowB, i, hb, qb, c);
    int wid = tid >> 6, lane = tid & 63;
    int quad = lane >> 4, lc = lane & 15;
#pragma unroll
    for (int sub = 0; sub < 2; ++sub) {
        {
            int n = nbase + sub * 64 + g;
            bool ok = (n < N_NODES);
            int d = sub ? dB : dA;
            const float* ar = sub ? c : a;
            float inv = 1.0f / fmaxf((float)d, 1.0f);
            short pk[8];
#pragma unroll
            for (int j = 0; j < 8; ++j) pk[j] = (short)f2bf(ar[j] * inv);
            uint4 hr = ok ? *(const uint4*)(hb + ((size_t)n << 6) + qb)
                          : make_uint4(0, 0, 0, 0);
            short* sp = sA + g * LSTR + q * 8;
            *(bf16x8*)(sp)     = *(bf16x8*)pk;   // mean -> k 0..31
            *(uint4*)(sp + 32) = hr;             // h    -> k 32..63
        }
        __syncthreads();                     // covers sBT on first sub too
        const short* sa = sA + (wid * 16 + lc) * LSTR + quad * 8;
        bf16x8 af0 = *(const bf16x8*)(sa);
        bf16x8 af1 = *(const bf16x8*)(sa + 32);
#pragma unroll
        for (int t = 0; t < 3; ++t) {
            const short* sbp = sBT + (t * 16 + lc) * LSTR + quad * 8;
            bf16x8 bf0 = *(const bf16x8*)(sbp);
            bf16x8 bf1 = *(const bf16x8*)(sbp + 32);
            f32x4 acc = {0.f, 0.f, 0.f, 0.f};
            acc = __builtin_amdgcn_mfma_f32_16x16x32_bf16(af0, bf0, acc, 0, 0, 0);
            acc = __builtin_amdgcn_mfma_f32_16x16x32_bf16(af1, bf1, acc, 0, 0, 0);
            int j = t * 16 + lc;
            if (j < D_OUT) {
                float bias = b2[j];
#pragma unroll
                for (int r = 0; r < 4; ++r) {
                    int n = nbase + sub * 64 + wid * 16 + (quad << 2) + r;
                    if (n < N_NODES)
                        nt_storef(acc[r] + bias, &out[(size_t)n * D_OUT + j]);
                }
            }
        }
        __syncthreads();
    }
}

extern "C" void kernel_launch(void* const* d_in, const int* in_sizes, int n_in,
                              void* d_out, int out_size, void* d_ws, size_t ws_size,
                              hipStream_t stream) {
    const float* x   = (const float*)d_in[0];
    const int*   ei  = (const int*)d_in[1];
    const int*   src = ei;                 // edge_index[0]
    const int*   dst = ei + N_EDGES;       // edge_index[1]
    const float* W1l = (const float*)d_in[2];
    const float* b1  = (const float*)d_in[3];
    const float* W1r = (const float*)d_in[4];
    const float* W2l = (const float*)d_in[5];
    const float* b2  = (const float*)d_in[6];
    const float* W2r = (const float*)d_in[7];
    float* out = (float*)d_out;

    // ws layout (int offsets), ~45.4 MB (round-8 layout):
    // bukspace[784*8192] @0 (slices, then glists alias) | gcnt[100352] @6422528 |
    // xl bf16 @6522880 | xr @8128512 | h @9734144  (each 100352 rows x 64B)
    int* iws = (int*)d_ws;
    unsigned int* bukspace = (unsigned int*)iws;
    int* gcnt   = iws + 6422528;
    unsigned short* xl = (unsigned short*)(iws + 6522880);
    unsigned short* xr = (unsigned short*)(iws + 8128512);
    unsigned short* h  = (unsigned short*)(iws + 9734144);

    k_front<<<PARTB + PBLK, 256, 0, stream>>>(src, dst, bukspace,
                                              x, W1l, W1r, b1, xl, xr);
    k_bagg1<<<NBUK, 256, 0, stream>>>(bukspace, xl, xr, h, gcnt);
    k_bagg2<<<NBUK, 256, 0, stream>>>(bukspace, gcnt, h, W2l, b2, W2r, out);
}

// Round 16
// 157.851 us; speedup vs baseline: 1.2679x; 1.2679x over previous
//
#include <hip/hip_runtime.h>

#define N_NODES 100000
#define N_EDGES 1250000
#define D_IN 64
#define D_HID 32
#define D_OUT 41
#define NBUK 784           // buckets of 128 nodes: 784*128 = 100352 >= 100000
#define BSH 7
#define PARTB 256          // partition blocks; each owns a private slice per bucket
#define BCHUNK 4883        // ceil(1.25M/256)
#define SCAP 32            // slice capacity: mean 6.23, tail ~0; 128B = 2 lines
#define BSTR 8192          // ints per bucket region = PARTB*SCAP (32KB/bucket)
#define PBLK 782           // proj blocks: 782*128 = 100096 rows (covers zero row)
#define ROWCAP 48          // per-node list capacity (Poisson(12.5) tail ~1e-15)
#define LSTR 88            // LDS row stride in shorts (MFMA tiles)
#define OSTR 72            // LDS out-tile row stride in shorts (144B, 16B-aligned)
#define ZERO_OFF 6400000   // byte offset of the all-zeros row (row 100000 * 64B)
#define SENT 0x01000000u   // valid edge words are < this; poison 0xAAAAAAAA is not

typedef short bf16x8 __attribute__((ext_vector_type(8)));
typedef float f32x4 __attribute__((ext_vector_type(4)));

__device__ __forceinline__ float bflo(unsigned int u) {
    union { unsigned int i; float f; } v; v.i = u << 16; return v.f;
}
__device__ __forceinline__ float bfhi(unsigned int u) {
    union { unsigned int i; float f; } v; v.i = u & 0xffff0000u; return v.f;
}
__device__ __forceinline__ unsigned short f2bf(float f) {
    union { float f; unsigned int i; } v; v.f = f;
    unsigned int x = v.i;
    return (unsigned short)((x + 0x7fffu + ((x >> 16) & 1u)) >> 16);  // RNE
}
__device__ __forceinline__ void acc8(float* a, uint4 u) {
    a[0] += bflo(u.x); a[1] += bfhi(u.x);
    a[2] += bflo(u.y); a[3] += bfhi(u.y);
    a[4] += bflo(u.z); a[5] += bfhi(u.z);
    a[6] += bflo(u.w); a[7] += bfhi(u.w);
}
__device__ __forceinline__ int padded8(int d) {
    int dd = d < ROWCAP ? d : ROWCAP;
    int p = (dd + 7) & ~7;
    if (p == 0) p = 8;
    return p;
}

// one 8-wide gather chunk (offsets from row[i..i+7]) from a 64B-row table.
__device__ __forceinline__ void chunk8(const int* row, int i, const char* tab,
                                       int qb, float* a) {
    int4 o0 = *(const int4*)(row + i);
    int4 o1 = *(const int4*)(row + i + 4);
    uint4 u0 = *(const uint4*)(tab + o0.x + qb);
    uint4 u1 = *(const uint4*)(tab + o0.y + qb);
    uint4 u2 = *(const uint4*)(tab + o0.z + qb);
    uint4 u3 = *(const uint4*)(tab + o0.w + qb);
    uint4 u4 = *(const uint4*)(tab + o1.x + qb);
    uint4 u5 = *(const uint4*)(tab + o1.y + qb);
    uint4 u6 = *(const uint4*)(tab + o1.z + qb);
    uint4 u7 = *(const uint4*)(tab + o1.w + qb);
    acc8(a, u0); acc8(a, u1); acc8(a, u2); acc8(a, u3);
    acc8(a, u4); acc8(a, u5); acc8(a, u6); acc8(a, u7);
}

// insert one slice word (if valid, i.e. below the poison sentinel) into lists.
__device__ __forceinline__ void ins(unsigned int w, int* lists, int* lcnt) {
    if (w < SENT) {
        int dl = (int)(w >> 17);
        int p = atomicAdd(&lcnt[dl], 1);
        if (p < ROWCAP) lists[dl * ROWCAP + p] = (int)((w & 0x1FFFFu) << 6);
    }
}

// ---- fused front (round-8 verified best): blocks [0,PARTB) partition edges
// into private 2-line bucket slices (LDS counter only: zero global atomics,
// poison-sentinel slice lengths; NORMAL stores — L2 write-combining is what
// keeps the scattered 4B slice writes cheap, measured r15); blocks
// [PARTB,PARTB+782) do the 128-row MFMA projection [xl|xr] = x @ [W1l|W1r]
// (+b1 into xr), full-line LDS-staged epilogue. ----
__global__ __launch_bounds__(256) void k_front(const int* __restrict__ src,
                                               const int* __restrict__ dst,
                                               unsigned int* __restrict__ buckets,
                                               const float* __restrict__ x,
                                               const float* __restrict__ W1l,
                                               const float* __restrict__ W1r,
                                               const float* __restrict__ b1,
                                               unsigned short* __restrict__ xl,
                                               unsigned short* __restrict__ xr) {
    __shared__ short smem[128 * LSTR + 64 * LSTR];   // proj tiles; part aliases
    int tid = threadIdx.x;
    if (blockIdx.x < PARTB) {
        // ---------------- single-pass private-slice partition ----------------
        int* lcnt = (int*)smem;             // [NBUK] per-block slice counters
        int bid = blockIdx.x;
        for (int i = tid; i < NBUK; i += 256) lcnt[i] = 0;
        __syncthreads();
        int e0 = bid * BCHUNK;
        int e1 = e0 + BCHUNK; if (e1 > N_EDGES) e1 = N_EDGES;
        int e = e0 + tid;
        for (; e + 768 < e1; e += 1024) {
            int d0 = dst[e],       s0 = src[e];
            int d1 = dst[e + 256], s1 = src[e + 256];
            int d2 = dst[e + 512], s2 = src[e + 512];
            int d3 = dst[e + 768], s3 = src[e + 768];
            int b0 = d0 >> BSH, p0 = atomicAdd(&lcnt[b0], 1);
            if (p0 < SCAP) buckets[(size_t)b0 * BSTR + bid * SCAP + p0] =
                (unsigned int)s0 | ((unsigned int)(d0 & 127) << 17);
            int b1i = d1 >> BSH, p1 = atomicAdd(&lcnt[b1i], 1);
            if (p1 < SCAP) buckets[(size_t)b1i * BSTR + bid * SCAP + p1] =
                (unsigned int)s1 | ((unsigned int)(d1 & 127) << 17);
            int b2 = d2 >> BSH, p2 = atomicAdd(&lcnt[b2], 1);
            if (p2 < SCAP) buckets[(size_t)b2 * BSTR + bid * SCAP + p2] =
                (unsigned int)s2 | ((unsigned int)(d2 & 127) << 17);
            int b3 = d3 >> BSH, p3 = atomicAdd(&lcnt[b3], 1);
            if (p3 < SCAP) buckets[(size_t)b3 * BSTR + bid * SCAP + p3] =
                (unsigned int)s3 | ((unsigned int)(d3 & 127) << 17);
        }
        for (; e < e1; e += 256) {
            int d = dst[e], s = src[e];
            int b = d >> BSH;
            int p = atomicAdd(&lcnt[b], 1);
            if (p < SCAP) buckets[(size_t)b * BSTR + bid * SCAP + p] =
                (unsigned int)s | ((unsigned int)(d & 127) << 17);
        }
        return;
    }
    // ---------------- MFMA projection (128 rows/block) ----------------
    short* sX  = smem;                    // 128 x LSTR
    short* sWT = smem + 128 * LSTR;       // 64 x LSTR
    int n0 = (blockIdx.x - PARTB) * 128;
    for (int i = tid; i < 1024; i += 256) {
        int k = i >> 4, c4 = i & 15;
        float4 v = (c4 < 8) ? ((const float4*)W1l)[k * 8 + c4]
                            : ((const float4*)W1r)[k * 8 + (c4 - 8)];
        int col = c4 * 4;
        sWT[(col + 0) * LSTR + k] = (short)f2bf(v.x);
        sWT[(col + 1) * LSTR + k] = (short)f2bf(v.y);
        sWT[(col + 2) * LSTR + k] = (short)f2bf(v.z);
        sWT[(col + 3) * LSTR + k] = (short)f2bf(v.w);
    }
    {
        int g = tid >> 1, q2 = tid & 1;   // 2 lanes/row, 32 floats each
        int n = n0 + g;
        short pk[32];
        if (n < N_NODES) {
            const float4* xp = (const float4*)(x + (size_t)n * D_IN + q2 * 32);
#pragma unroll
            for (int i = 0; i < 8; ++i) {
                float4 f = xp[i];
                pk[i * 4 + 0] = (short)f2bf(f.x);
                pk[i * 4 + 1] = (short)f2bf(f.y);
                pk[i * 4 + 2] = (short)f2bf(f.z);
                pk[i * 4 + 3] = (short)f2bf(f.w);
            }
        } else {
#pragma unroll
            for (int i = 0; i < 32; ++i) pk[i] = 0;
        }
        short* sp = sX + g * LSTR + q2 * 32;
        *(bf16x8*)(sp)      = *(bf16x8*)(pk);
        *(bf16x8*)(sp + 8)  = *(bf16x8*)(pk + 8);
        *(bf16x8*)(sp + 16) = *(bf16x8*)(pk + 16);
        *(bf16x8*)(sp + 24) = *(bf16x8*)(pk + 24);
    }
    __syncthreads();
    int wid = tid >> 6, lane = tid & 63;
    int quad = lane >> 4, lc = lane & 15;
    // load BOTH row-half A-fragments before aliasing sX with the out tile
    const short* saA = sX + (wid * 16 + lc) * LSTR + quad * 8;
    const short* saB = sX + ((wid + 4) * 16 + lc) * LSTR + quad * 8;
    bf16x8 afA0 = *(const bf16x8*)(saA);
    bf16x8 afA1 = *(const bf16x8*)(saA + 32);
    bf16x8 afB0 = *(const bf16x8*)(saB);
    bf16x8 afB1 = *(const bf16x8*)(saB + 32);
    __syncthreads();                        // all frags in regs; sX reusable
    short* sO = sX;                         // 128 x OSTR out tile (18.4KB <= sX)
#pragma unroll
    for (int mm = 0; mm < 2; ++mm) {
        int m0 = (wid + mm * 4) * 16;
        bf16x8 af0 = mm ? afB0 : afA0;
        bf16x8 af1 = mm ? afB1 : afA1;
#pragma unroll
        for (int t = 0; t < 4; ++t) {
            const short* sbp = sWT + (t * 16 + lc) * LSTR + quad * 8;
            bf16x8 bf0 = *(const bf16x8*)(sbp);
            bf16x8 bf1 = *(const bf16x8*)(sbp + 32);
            f32x4 acc = {0.f, 0.f, 0.f, 0.f};
            acc = __builtin_amdgcn_mfma_f32_16x16x32_bf16(af0, bf0, acc, 0, 0, 0);
            acc = __builtin_amdgcn_mfma_f32_16x16x32_bf16(af1, bf1, acc, 0, 0, 0);
            int col = t * 16 + lc;
            float bias = (col >= 32) ? b1[col - 32] : 0.f;
#pragma unroll
            for (int r = 0; r < 4; ++r)
                sO[(m0 + (quad << 2) + r) * OSTR + col] = (short)f2bf(acc[r] + bias);
        }
    }
    __syncthreads();
    {
        int g = tid >> 1, q2 = tid & 1;     // q2=0 -> xl row, q2=1 -> xr row
        int n = n0 + g;
        const short* srow = sO + g * OSTR + q2 * 32;
        uint4 v0, v1, v2, v3;
        if (n < N_NODES) {
            v0 = *(const uint4*)(srow);
            v1 = *(const uint4*)(srow + 8);
            v2 = *(const uint4*)(srow + 16);
            v3 = *(const uint4*)(srow + 24);
        } else {
            v0 = v1 = v2 = v3 = make_uint4(0, 0, 0, 0);  // zero rows incl. ZERO_OFF
        }
        char* base = (char*)(q2 ? xr : xl) + ((size_t)n << 6);
        *(uint4*)(base)      = v0;
        *(uint4*)(base + 16) = v1;
        *(uint4*)(base + 32) = v2;
        *(uint4*)(base + 48) = v3;
    }
}

// ---- layer1: one block per 128-node bucket. Dense coalesced sentinel-scan
// of the bucket region (poison marks slice ends; no count arrays) -> LDS
// lists -> predicated dump over the bucket region (alias; reads done) ->
// dual-node chunk8 gather -> h = bf16(relu(mean + xr)). ----
__global__ __launch_bounds__(256) void k_bagg1(unsigned int* __restrict__ bukspace,
                                               const unsigned short* __restrict__ xl,
                                               const unsigned short* __restrict__ xr,
                                               unsigned short* __restrict__ h,
                                               int* __restrict__ gcnt) {
    __shared__ int lists[128 * ROWCAP];
    __shared__ int lcnt[128];
    int tid = threadIdx.x, b = blockIdx.x;
    if (tid < 128) lcnt[tid] = 0;
    __syncthreads();
    const uint4* bk4 = (const uint4*)(bukspace + (size_t)b * BSTR);
#pragma unroll
    for (int k = 0; k < BSTR / 4 / 256; ++k) {      // 8 coalesced uint4/thread
        uint4 w = bk4[tid + k * 256];
        ins(w.x, lists, lcnt);
        ins(w.y, lists, lcnt);
        ins(w.z, lists, lcnt);
        ins(w.w, lists, lcnt);
    }
    __syncthreads();
    if (tid < 128) {
        int c = lcnt[tid];
        int cc = c < ROWCAP ? c : ROWCAP;
        int ce = (cc + 7) & ~7;
        if (ce == 0) ce = 8;                // min-pad: chunk 0 always valid
        for (int s = cc; s < ce; ++s) lists[tid * ROWCAP + s] = ZERO_OFF;
    }
    __syncthreads();
    int nbase = b << BSH;
    // predicated dump over the (fully consumed) bucket region: glists alias
    int* glists = (int*)(bukspace + (size_t)b * BSTR);
    for (int i4 = tid; i4 < 128 * 12; i4 += 256) {
        int li = i4 / 12, c4 = i4 % 12;
        if (c4 * 4 < padded8(lcnt[li]))
            *(uint4*)(glists + li * ROWCAP + c4 * 4) =
                *(const uint4*)(lists + li * ROWCAP + c4 * 4);
    }
    if (tid < 128) gcnt[nbase + tid] = lcnt[tid];
    // dual-node chunk8 gather
    int g = tid >> 2, q = tid & 3, qb = q << 4;
    int nA = nbase + g, nB = nbase + g + 64;
    int dA = lcnt[g], dB = lcnt[g + 64];
    int pA = padded8(dA), pB = padded8(dB);
    const int* rowA = lists + g * ROWCAP;
    const int* rowB = lists + (g + 64) * ROWCAP;
    const char* xlb = (const char*)xl;
    float a[8] = {0.f, 0.f, 0.f, 0.f, 0.f, 0.f, 0.f, 0.f};
    float c[8] = {0.f, 0.f, 0.f, 0.f, 0.f, 0.f, 0.f, 0.f};
    chunk8(rowA, 0, xlb, qb, a);
    chunk8(rowB, 0, xlb, qb, c);
    for (int i = 8; i < pA; i += 8) chunk8(rowA, i, xlb, qb, a);
    for (int i = 8; i < pB; i += 8) chunk8(rowB, i, xlb, qb, c);
#pragma unroll
    for (int half = 0; half < 2; ++half) {
        int n = half ? nB : nA;
        int d = half ? dB : dA;
        const float* ar = half ? c : a;
        if (n >= N_NODES) {
            *(uint4*)((char*)h + ((size_t)n << 6) + qb) = make_uint4(0, 0, 0, 0);
            continue;
        }
        float inv = 1.0f / fmaxf((float)d, 1.0f);
        uint4 rr = *(const uint4*)((const char*)xr + ((size_t)n << 6) + qb);
        float o0 = fmaxf(ar[0] * inv + bflo(rr.x), 0.f);
        float o1 = fmaxf(ar[1] * inv + bfhi(rr.x), 0.f);
        float o2 = fmaxf(ar[2] * inv + bflo(rr.y), 0.f);
        float o3 = fmaxf(ar[3] * inv + bfhi(rr.y), 0.f);
        float o4 = fmaxf(ar[4] * inv + bflo(rr.z), 0.f);
        float o5 = fmaxf(ar[5] * inv + bfhi(rr.z), 0.f);
        float o6 = fmaxf(ar[6] * inv + bflo(rr.w), 0.f);
        float o7 = fmaxf(ar[7] * inv + bfhi(rr.w), 0.f);
        uint4 o;
        o.x = ((unsigned int)f2bf(o1) << 16) | f2bf(o0);
        o.y = ((unsigned int)f2bf(o3) << 16) | f2bf(o2);
        o.z = ((unsigned int)f2bf(o5) << 16) | f2bf(o4);
        o.w = ((unsigned int)f2bf(o7) << 16) | f2bf(o6);
        *(uint4*)((char*)h + ((size_t)n << 6) + qb) = o;
    }
}

// ---- layer2: lists read DIRECTLY from global (19.7KB LDS, high occupancy),
// chunk8 gather over h, then 2x 64-row MFMA epilogue:
// out = [mean|h] @ [W2l;W2r] + b2. ----
__global__ __launch_bounds__(256) void k_bagg2(const unsigned int* __restrict__ bukspace,
                                               const int* __restrict__ gcnt,
                                               const unsigned short* __restrict__ h,
                                               const float* __restrict__ W2l,
                                               const float* __restrict__ b2,
                                               const float* __restrict__ W2r,
                                               float* __restrict__ out) {
    __shared__ short sBT[48 * LSTR];
    __shared__ short sA[64 * LSTR];
    int tid = threadIdx.x, b = blockIdx.x;
    int nbase = b << BSH;
    for (int i = tid; i < 48 * 64; i += 256) {
        int col = i >> 6, kk = i & 63;
        float v = 0.f;
        if (col < D_OUT) v = (kk < 32) ? W2l[kk * D_OUT + col] : W2r[(kk - 32) * D_OUT + col];
        sBT[col * LSTR + kk] = (short)f2bf(v);
    }
    const int* glists = (const int*)(bukspace + (size_t)b * BSTR);
    int g = tid >> 2, q = tid & 3, qb = q << 4;
    int dA = gcnt[nbase + g], dB = gcnt[nbase + g + 64];
    int pA = padded8(dA), pB = padded8(dB);
    const int* rowA = glists + g * ROWCAP;
    const int* rowB = glists + (g + 64) * ROWCAP;
    const char* hb = (const char*)h;
    float a[8] = {0.f, 0.f, 0.f, 0.f, 0.f, 0.f, 0.f, 0.f};
    float c[8] = {0.f, 0.f, 0.f, 0.f, 0.f, 0.f, 0.f, 0.f};
    chunk8(rowA, 0, hb, qb, a);
    chunk8(rowB, 0, hb, qb, c);
    for (int i = 8; i < pA; i += 8) chunk8(rowA, i, hb, qb, a);
    for (int i = 8; i < pB; i += 8) chunk8(rowB, i, hb, qb, c);
    int wid = tid >> 6, lane = tid & 63;
    int quad = lane >> 4, lc = lane & 15;
#pragma unroll
    for (int sub = 0; sub < 2; ++sub) {
        {
            int n = nbase + sub * 64 + g;
            bool ok = (n < N_NODES);
            int d = sub ? dB : dA;
            const float* ar = sub ? c : a;
            float inv = 1.0f / fmaxf((float)d, 1.0f);
            short pk[8];
#pragma unroll
            for (int j = 0; j < 8; ++j) pk[j] = (short)f2bf(ar[j] * inv);
            uint4 hr = ok ? *(const uint4*)(hb + ((size_t)n << 6) + qb)
                          : make_uint4(0, 0, 0, 0);
            short* sp = sA + g * LSTR + q * 8;
            *(bf16x8*)(sp)     = *(bf16x8*)pk;   // mean -> k 0..31
            *(uint4*)(sp + 32) = hr;             // h    -> k 32..63
        }
        __syncthreads();                     // covers sBT on first sub too
        const short* sa = sA + (wid * 16 + lc) * LSTR + quad * 8;
        bf16x8 af0 = *(const bf16x8*)(sa);
        bf16x8 af1 = *(const bf16x8*)(sa + 32);
#pragma unroll
        for (int t = 0; t < 3; ++t) {
            const short* sbp = sBT + (t * 16 + lc) * LSTR + quad * 8;
            bf16x8 bf0 = *(const bf16x8*)(sbp);
            bf16x8 bf1 = *(const bf16x8*)(sbp + 32);
            f32x4 acc = {0.f, 0.f, 0.f, 0.f};
            acc = __builtin_amdgcn_mfma_f32_16x16x32_bf16(af0, bf0, acc, 0, 0, 0);
            acc = __builtin_amdgcn_mfma_f32_16x16x32_bf16(af1, bf1, acc, 0, 0, 0);
            int j = t * 16 + lc;
            if (j < D_OUT) {
                float bias = b2[j];
#pragma unroll
                for (int r = 0; r < 4; ++r) {
                    int n = nbase + sub * 64 + wid * 16 + (quad << 2) + r;
                    if (n < N_NODES) out[(size_t)n * D_OUT + j] = acc[r] + bias;
                }
            }
        }
        __syncthreads();
    }
}

extern "C" void kernel_launch(void* const* d_in, const int* in_sizes, int n_in,
                              void* d_out, int out_size, void* d_ws, size_t ws_size,
                              hipStream_t stream) {
    const float* x   = (const float*)d_in[0];
    const int*   ei  = (const int*)d_in[1];
    const int*   src = ei;                 // edge_index[0]
    const int*   dst = ei + N_EDGES;       // edge_index[1]
    const float* W1l = (const float*)d_in[2];
    const float* b1  = (const float*)d_in[3];
    const float* W1r = (const float*)d_in[4];
    const float* W2l = (const float*)d_in[5];
    const float* b2  = (const float*)d_in[6];
    const float* W2r = (const float*)d_in[7];
    float* out = (float*)d_out;

    // ws layout (int offsets), ~45.4 MB:
    // bukspace[784*8192] @0 (slices, then glists alias) | gcnt[100352] @6422528 |
    // xl bf16 @6522880 | xr @8128512 | h @9734144  (each 100352 rows x 64B)
    int* iws = (int*)d_ws;
    unsigned int* bukspace = (unsigned int*)iws;
    int* gcnt   = iws + 6422528;
    unsigned short* xl = (unsigned short*)(iws + 6522880);
    unsigned short* xr = (unsigned short*)(iws + 8128512);
    unsigned short* h  = (unsigned short*)(iws + 9734144);

    k_front<<<PARTB + PBLK, 256, 0, stream>>>(src, dst, bukspace,
                                              x, W1l, W1r, b1, xl, xr);
    k_bagg1<<<NBUK, 256, 0, stream>>>(bukspace, xl, xr, h, gcnt);
    k_bagg2<<<NBUK, 256, 0, stream>>>(bukspace, gcnt, h, W2l, b2, W2r, out);
}